// Round 6
// baseline (228.379 us; speedup 1.0000x reference)
//
#include <hip/hip_runtime.h>
#include <hip/hip_bf16.h>
#include <hip/hip_cooperative_groups.h>
#include <math.h>

#define B_ROWS 4096
#define D_DIM  256
#define N_TOT  8192            // 2B
#define E2     7.38905609893065f   // exp(2) = diagonal term of the row sum
#define NTILE  64              // 8192 / 128
#define NBLK   (NTILE * (NTILE + 1) / 2)   // 2080 upper-triangle tile pairs

typedef __attribute__((ext_vector_type(4))) float f32x4;

namespace cg = cooperative_groups;

__device__ __forceinline__ void async_copy16(const void* gptr, void* lptr) {
    // NOTE: lptr is the WAVE-UNIFORM base; HW scatters lane*16 itself.
    __builtin_amdgcn_global_load_lds(
        (const __attribute__((address_space(1))) unsigned int*)gptr,
        (__attribute__((address_space(3))) unsigned int*)lptr,
        16 /*bytes*/, 0 /*offset*/, 0 /*aux*/);
}

__device__ __forceinline__ void decode_tri(int bid, int& bi, int& bj) {
    int b = 0, rowStart = 0;
    while (rowStart + (NTILE - b) <= bid) { rowStart += NTILE - b; ++b; }
    bi = b; bj = b + (bid - rowStart);
}

// ---------------------------------------------------------------------------
// One 128x128 tile pair of S = Z*Z^T (fp8 e4m3), epilogue exp(2s) row/col
// sums -> atomicAdd into denom. BK=128 (2 K-iters), 16+16 KB LDS, XOR
// swizzle on the global source side (bank-conflict-free, verified R3: 4.2M->0).
// ---------------------------------------------------------------------------
__device__ __forceinline__ void gemm_tile(
        const unsigned char* __restrict__ Z, float* __restrict__ denom,
        unsigned char* As, unsigned char* Bs, int bi, int bj, int tid) {
    const int lane   = tid & 63;
    const int wv     = tid >> 6;
    const int wave_m = wv >> 1;
    const int wave_n = wv & 1;
    const int m16    = lane & 15;
    const int quad   = lane >> 4;
    const int lrow   = lane >> 3;      // staging: local row in 8-row group
    const int lchk   = lane & 7;       // 16B chunk slot
    const int rowBase = bi * 128;
    const int colBase = bj * 128;

    f32x4 acc[4][4];
    #pragma unroll
    for (int i = 0; i < 4; ++i)
        #pragma unroll
        for (int j = 0; j < 4; ++j) acc[i][j] = (f32x4){0.f, 0.f, 0.f, 0.f};

    for (int kt = 0; kt < 2; ++kt) {
        const int k0 = kt * 128;           // byte offset in K (1B/elem)
        __syncthreads();   // prev LDS reads (or prev tile) done
        #pragma unroll
        for (int pp = 0; pp < 4; ++pp) {
            const int r = wv * 32 + pp * 8 + lrow;   // local row 0..127
            const int g = lchk ^ (r & 7);            // swizzled chunk
            async_copy16(Z + (size_t)(rowBase + r) * D_DIM + k0 + g * 16,
                         As + (wv * 32 + pp * 8) * 128);
            async_copy16(Z + (size_t)(colBase + r) * D_DIM + k0 + g * 16,
                         Bs + (wv * 32 + pp * 8) * 128);
        }
        __syncthreads();   // drains vmcnt: staging complete

        #pragma unroll
        for (int kt2 = 0; kt2 < 4; ++kt2) {
            const int chunk = kt2 * 2 + (quad >> 1);    // 16B chunk index
            const int half  = (quad & 1) * 8;
            const int sc    = chunk ^ (m16 & 7);        // swizzled
            long af[4], bfr[4];
            #pragma unroll
            for (int mi = 0; mi < 4; ++mi) {
                const int r = wave_m * 64 + mi * 16 + m16;
                af[mi] = *(const long*)(As + r * 128 + sc * 16 + half);
            }
            #pragma unroll
            for (int ni = 0; ni < 4; ++ni) {
                const int r = wave_n * 64 + ni * 16 + m16;
                bfr[ni] = *(const long*)(Bs + r * 128 + sc * 16 + half);
            }
            #pragma unroll
            for (int mi = 0; mi < 4; ++mi)
                #pragma unroll
                for (int ni = 0; ni < 4; ++ni)
                    acc[mi][ni] = __builtin_amdgcn_mfma_f32_16x16x32_fp8_fp8(
                        af[mi], bfr[ni], acc[mi][ni], 0, 0, 0);
        }
    }

    // epilogue: exp(2s); row partials + (off-diag) col partials.
    // C/D layout: col = lane&15, row = quad*4 + reg  [m89, dtype-indep]
    float cs[4] = {0.f, 0.f, 0.f, 0.f};
    float rs[4][4];
    #pragma unroll
    for (int mi = 0; mi < 4; ++mi)
        #pragma unroll
        for (int r = 0; r < 4; ++r) {
            float s = 0.f;
            #pragma unroll
            for (int ni = 0; ni < 4; ++ni) {
                const float e = __expf(2.0f * acc[mi][ni][r]);
                s += e;
                cs[ni] += e;
            }
            rs[mi][r] = s;
        }
    #pragma unroll
    for (int off = 1; off < 16; off <<= 1)
        #pragma unroll
        for (int mi = 0; mi < 4; ++mi)
            #pragma unroll
            for (int r = 0; r < 4; ++r)
                rs[mi][r] += __shfl_xor(rs[mi][r], off, 64);
    if (m16 == 0) {
        #pragma unroll
        for (int mi = 0; mi < 4; ++mi)
            #pragma unroll
            for (int r = 0; r < 4; ++r)
                atomicAdd(&denom[rowBase + wave_m * 64 + mi * 16 + quad * 4 + r],
                          rs[mi][r]);
    }
    if (bi != bj) {
        #pragma unroll
        for (int off = 16; off < 64; off <<= 1)
            #pragma unroll
            for (int ni = 0; ni < 4; ++ni)
                cs[ni] += __shfl_xor(cs[ni], off, 64);
        if (lane < 16) {
            #pragma unroll
            for (int ni = 0; ni < 4; ++ni)
                atomicAdd(&denom[colBase + wave_n * 64 + ni * 16 + m16], cs[ni]);
        }
    }
}

// Normalize one row pair (wave-per-row): fp8 e4m3 write + positive dot.
__device__ __forceinline__ void norm_row(
        const float* __restrict__ q, const float* __restrict__ p,
        unsigned char* __restrict__ Z, float* __restrict__ pospart,
        int row, int lane) {
    const f32x4 q4 = *(const f32x4*)(q + (size_t)row * D_DIM + lane * 4);
    const f32x4 p4 = *(const f32x4*)(p + (size_t)row * D_DIM + lane * 4);
    float a = q4[0]*q4[0] + q4[1]*q4[1] + q4[2]*q4[2] + q4[3]*q4[3];
    float b = p4[0]*p4[0] + p4[1]*p4[1] + p4[2]*p4[2] + p4[3]*p4[3];
    float c = q4[0]*p4[0] + q4[1]*p4[1] + q4[2]*p4[2] + q4[3]*p4[3];
    #pragma unroll
    for (int off = 1; off < 64; off <<= 1) {
        a += __shfl_xor(a, off);
        b += __shfl_xor(b, off);
        c += __shfl_xor(c, off);
    }
    const float rq = 1.0f / fmaxf(sqrtf(a), 1e-12f);
    const float rp = 1.0f / fmaxf(sqrtf(b), 1e-12f);
    int zq = 0, zp = 0;
    zq = __builtin_amdgcn_cvt_pk_fp8_f32(q4[0]*rq, q4[1]*rq, zq, false);
    zq = __builtin_amdgcn_cvt_pk_fp8_f32(q4[2]*rq, q4[3]*rq, zq, true);
    zp = __builtin_amdgcn_cvt_pk_fp8_f32(p4[0]*rp, p4[1]*rp, zp, false);
    zp = __builtin_amdgcn_cvt_pk_fp8_f32(p4[2]*rp, p4[3]*rp, zp, true);
    ((int*)(Z + (size_t)row * D_DIM))[lane]            = zq;
    ((int*)(Z + (size_t)(B_ROWS + row) * D_DIM))[lane] = zp;
    if (lane == 0) pospart[row] = c * rq * rp;
}

// Final reduction: loss = (sum log(denom - e^2) - 4*sum pospart) / 8192.
// denom read via atomicAdd(+0.0f) -> coherent-point read, no stale-L2 risk.
__device__ __forceinline__ void finalize_fn(
        float* denom, const float* __restrict__ pospart, float* out, int tid) {
    float s = 0.f;
    #pragma unroll
    for (int i = 0; i < N_TOT / 256; ++i)
        s += logf(atomicAdd(&denom[i * 256 + tid], 0.0f) - E2);
    float pp = 0.f;
    #pragma unroll
    for (int i = 0; i < B_ROWS / 256; ++i) pp += pospart[i * 256 + tid];
    s -= 4.0f * pp;
    #pragma unroll
    for (int off = 32; off > 0; off >>= 1) s += __shfl_down(s, off);
    __shared__ float red[4];
    if ((tid & 63) == 0) red[tid >> 6] = s;
    __syncthreads();
    if (tid == 0)
        out[0] = (red[0] + red[1] + red[2] + red[3]) / (float)N_TOT;
}

// ---------------------------------------------------------------------------
// Cooperative fused kernel (grid sized from an occupancy QUERY, not a guess).
// launch_bounds(256,2): reg cap 256 >> ~140 needed -> no spill (R4's (256,5)
// cap of ~102 spilled 100MB scratch).
// ---------------------------------------------------------------------------
__global__ __launch_bounds__(256, 2) void fused_kernel(
        const float* __restrict__ q, const float* __restrict__ p,
        unsigned char* __restrict__ Z, float* __restrict__ pospart,
        float* __restrict__ denom, float* __restrict__ out) {
    __shared__ unsigned char As[128 * 128];   // 16 KB
    __shared__ unsigned char Bs[128 * 128];   // 16 KB
    const int tid  = threadIdx.x;
    const int lane = tid & 63;
    const int wv   = tid >> 6;
    const int G    = gridDim.x;

    // Phase 1: normalize + zero denom (atomicExch: keeps ALL denom traffic at
    // the coherent point -- no plain-store line to go stale in an L2).
    for (int i = blockIdx.x * 256 + tid; i < N_TOT; i += G * 256)
        atomicExch(&denom[i], 0.0f);
    for (int row = blockIdx.x * 4 + wv; row < B_ROWS; row += G * 4)
        norm_row(q, p, Z, pospart, row, lane);
    __threadfence();
    cg::this_grid().sync();

    // Phase 2: contiguous chunk of tile-pairs per block (A-tile L2 locality).
    const int per = NBLK / G, rem = NBLK % G;
    const int extra = (blockIdx.x < rem) ? 1 : 0;
    int start = blockIdx.x * per + (blockIdx.x < rem ? blockIdx.x : rem);
    int end   = start + per + extra;
    for (int bid = start; bid < end; ++bid) {
        int bi, bj;
        decode_tri(bid, bi, bj);
        gemm_tile(Z, denom, As, Bs, bi, bj, tid);
    }
    __threadfence();
    cg::this_grid().sync();

    // Phase 3: block 0 reduces.
    if (blockIdx.x == 0) finalize_fn(denom, pospart, out, tid);
}

// ---------------------------------------------------------------------------
// Fallback path (2 dispatches, no co-residency assumption, deadlock-free).
// ---------------------------------------------------------------------------
__global__ __launch_bounds__(256) void norm_kernel(
        const float* __restrict__ q, const float* __restrict__ p,
        unsigned char* __restrict__ Z, float* __restrict__ pospart,
        float* __restrict__ denom, unsigned int* __restrict__ counter) {
    const int tid = threadIdx.x;
    if (blockIdx.x < 32) denom[blockIdx.x * 256 + tid] = 0.0f;
    if (blockIdx.x == 0 && tid == 0) *counter = 0u;
    norm_row(q, p, Z, pospart, blockIdx.x * 4 + (tid >> 6), tid & 63);
}

__global__ __launch_bounds__(256, 2) void gemm_fb(
        const unsigned char* __restrict__ Z, float* __restrict__ denom,
        const float* __restrict__ pospart, unsigned int* __restrict__ counter,
        float* __restrict__ out) {
    __shared__ unsigned char As[128 * 128];
    __shared__ unsigned char Bs[128 * 128];
    const int tid = threadIdx.x;
    int bi, bj;
    decode_tri(blockIdx.x, bi, bj);
    gemm_tile(Z, denom, As, Bs, bi, bj, tid);
    // last block to finish performs the final reduction
    __threadfence();
    __shared__ int lastflag;
    if (tid == 0) lastflag = (atomicAdd(counter, 1u) == NBLK - 1) ? 1 : 0;
    __syncthreads();
    if (lastflag) finalize_fn(denom, pospart, out, tid);
}

extern "C" void kernel_launch(void* const* d_in, const int* in_sizes, int n_in,
                              void* d_out, int out_size, void* d_ws, size_t ws_size,
                              hipStream_t stream) {
    const float* q = (const float*)d_in[0];
    const float* p = (const float*)d_in[1];
    // d_in[2] (neg) is normalized in the original but never used in the loss.
    float* out = (float*)d_out;

    // Workspace: Z fp8 [8192*256] (2 MiB) | denom f32 [8192] | pospart f32
    // [4096] | done-counter u32
    unsigned char* Z = (unsigned char*)d_ws;
    float* denom   = (float*)((char*)d_ws + (size_t)N_TOT * D_DIM);
    float* pospart = denom + N_TOT;
    unsigned int* counter = (unsigned int*)(pospart + B_ROWS);

    int nb = 0;
    hipError_t qe = hipOccupancyMaxActiveBlocksPerMultiprocessor(
        &nb, fused_kernel, 256, 0);
    if (qe == hipSuccess && nb >= 1) {
        const int k = nb < 3 ? nb : 3;
        void* args[] = {(void*)&q, (void*)&p, (void*)&Z, (void*)&pospart,
                        (void*)&denom, (void*)&out};
        hipError_t le = hipLaunchCooperativeKernel(
            (const void*)fused_kernel, dim3(k * 256), dim3(256), args, 0, stream);
        if (le == hipSuccess) return;
    }
    (void)hipGetLastError();   // clear any launch error before fallback

    hipLaunchKernelGGL(norm_kernel, dim3(B_ROWS / 4), dim3(256), 0, stream,
                       q, p, Z, pospart, denom, counter);
    hipLaunchKernelGGL(gemm_fb, dim3(NBLK), dim3(256), 0, stream,
                       Z, denom, pospart, counter, out);
}

// Round 7
// 209.659 us; speedup vs baseline: 1.0893x; 1.0893x over previous
//
#include <hip/hip_runtime.h>
#include <hip/hip_bf16.h>
#include <math.h>

#define B_ROWS 4096
#define D_DIM  256
#define N_TOT  8192            // 2B
#define E2     7.38905609893065f   // exp(2) = diagonal term of the row sum
#define NTILE  64              // 8192 / 128
#define NBLK   (NTILE * (NTILE + 1) / 2)   // 2080 upper-triangle tile pairs

typedef __attribute__((ext_vector_type(4))) float f32x4;

__device__ __forceinline__ void async_copy16(const void* gptr, void* lptr) {
    // NOTE: lptr is the WAVE-UNIFORM base; HW scatters lane*16 itself.
    __builtin_amdgcn_global_load_lds(
        (const __attribute__((address_space(1))) unsigned int*)gptr,
        (__attribute__((address_space(3))) unsigned int*)lptr,
        16 /*bytes*/, 0 /*offset*/, 0 /*aux*/);
}

__device__ __forceinline__ void decode_tri(int bid, int& bi, int& bj) {
    int b = 0, rowStart = 0;
    while (rowStart + (NTILE - b) <= bid) { rowStart += NTILE - b; ++b; }
    bi = b; bj = b + (bid - rowStart);
}

// ---------------------------------------------------------------------------
// Kernel 1: L2-normalize q,p -> fp8 e4m3 Z[8192][256B] (wave per row);
// pospart[row] = zq.zp ; zero denom ; reset done-counter.
// ---------------------------------------------------------------------------
__global__ __launch_bounds__(256) void norm_kernel(
        const float* __restrict__ q, const float* __restrict__ p,
        unsigned char* __restrict__ Z, float* __restrict__ pospart,
        float* __restrict__ denom, unsigned int* __restrict__ counter) {
    const int tid  = threadIdx.x;
    const int lane = tid & 63;
    const int row  = blockIdx.x * 4 + (tid >> 6);
    if (blockIdx.x < 32) denom[blockIdx.x * 256 + tid] = 0.0f;
    if (blockIdx.x == 0 && tid == 0) *counter = 0u;

    const f32x4 q4 = *(const f32x4*)(q + (size_t)row * D_DIM + lane * 4);
    const f32x4 p4 = *(const f32x4*)(p + (size_t)row * D_DIM + lane * 4);
    float a = q4[0]*q4[0] + q4[1]*q4[1] + q4[2]*q4[2] + q4[3]*q4[3];
    float b = p4[0]*p4[0] + p4[1]*p4[1] + p4[2]*p4[2] + p4[3]*p4[3];
    float c = q4[0]*p4[0] + q4[1]*p4[1] + q4[2]*p4[2] + q4[3]*p4[3];
    #pragma unroll
    for (int off = 1; off < 64; off <<= 1) {   // butterfly: all lanes get sums
        a += __shfl_xor(a, off);
        b += __shfl_xor(b, off);
        c += __shfl_xor(c, off);
    }
    const float rq = 1.0f / fmaxf(sqrtf(a), 1e-12f);
    const float rp = 1.0f / fmaxf(sqrtf(b), 1e-12f);
    int zq = 0, zp = 0;
    zq = __builtin_amdgcn_cvt_pk_fp8_f32(q4[0]*rq, q4[1]*rq, zq, false);
    zq = __builtin_amdgcn_cvt_pk_fp8_f32(q4[2]*rq, q4[3]*rq, zq, true);
    zp = __builtin_amdgcn_cvt_pk_fp8_f32(p4[0]*rp, p4[1]*rp, zp, false);
    zp = __builtin_amdgcn_cvt_pk_fp8_f32(p4[2]*rp, p4[3]*rp, zp, true);
    ((int*)(Z + (size_t)row * D_DIM))[lane]            = zq;
    ((int*)(Z + (size_t)(B_ROWS + row) * D_DIM))[lane] = zp;
    if (lane == 0) pospart[row] = c * rq * rp;
}

// ---------------------------------------------------------------------------
// Kernel 2: one 128x128 tile pair of S = Z*Z^T (fp8 e4m3) per block,
// upper-triangle (symmetry): epilogue exp(2s) row sums + (off-diag) col sums
// atomicAdd'ed into denom. BK=128 -> 2 barrier-pairs/tile. 16+16 KB LDS,
// XOR swizzle on the global source side (bank-balanced b64 reads).
// launch_bounds(256,3): reg cap 170 (R3-verified no-spill regime; (256,5)
// capped ~102 and spilled 100 MB scratch in R4).
// The LAST block to finish folds in the final reduction (done-counter) --
// no grid barrier, no co-residency assumption (coop grid.sync cost ~250us
// of idle spin in R6 -- abandoned).
// ---------------------------------------------------------------------------
__global__ __launch_bounds__(256, 3) void gemm_fin(
        const unsigned char* __restrict__ Z, float* __restrict__ denom,
        const float* __restrict__ pospart, unsigned int* __restrict__ counter,
        float* __restrict__ out) {
    __shared__ unsigned char As[128 * 128];   // 16 KB, row stride 128 B
    __shared__ unsigned char Bs[128 * 128];   // 16 KB
    const int tid    = threadIdx.x;
    const int lane   = tid & 63;
    const int wv     = tid >> 6;      // wave id 0..3
    const int wave_m = wv >> 1;       // 0..1  (row half)
    const int wave_n = wv & 1;        // 0..1  (col half)
    const int m16    = lane & 15;
    const int quad   = lane >> 4;
    const int lrow   = lane >> 3;     // staging: local row in 8-row group
    const int lchk   = lane & 7;      // 16B chunk slot

    int bi, bj;
    decode_tri(blockIdx.x, bi, bj);
    const int rowBase = bi * 128;
    const int colBase = bj * 128;

    f32x4 acc[4][4];
    #pragma unroll
    for (int i = 0; i < 4; ++i)
        #pragma unroll
        for (int j = 0; j < 4; ++j) acc[i][j] = (f32x4){0.f, 0.f, 0.f, 0.f};

    for (int kt = 0; kt < 2; ++kt) {
        const int k0 = kt * 128;           // byte offset in K (1B/elem)
        __syncthreads();   // prev iter's LDS reads done before overwrite
        #pragma unroll
        for (int pp = 0; pp < 4; ++pp) {
            const int r = wv * 32 + pp * 8 + lrow;   // local row 0..127
            const int g = lchk ^ (r & 7);            // swizzled 16B chunk
            async_copy16(Z + (size_t)(rowBase + r) * D_DIM + k0 + g * 16,
                         As + (wv * 32 + pp * 8) * 128);
            async_copy16(Z + (size_t)(colBase + r) * D_DIM + k0 + g * 16,
                         Bs + (wv * 32 + pp * 8) * 128);
        }
        __syncthreads();   // drains vmcnt: staging complete

        #pragma unroll
        for (int kt2 = 0; kt2 < 4; ++kt2) {
            const int chunk = kt2 * 2 + (quad >> 1);    // 16B chunk index
            const int half  = (quad & 1) * 8;
            const int sc    = chunk ^ (m16 & 7);        // swizzled
            long af[4], bfr[4];
            #pragma unroll
            for (int mi = 0; mi < 4; ++mi) {
                const int r = wave_m * 64 + mi * 16 + m16;
                af[mi] = *(const long*)(As + r * 128 + sc * 16 + half);
            }
            #pragma unroll
            for (int ni = 0; ni < 4; ++ni) {
                const int r = wave_n * 64 + ni * 16 + m16;
                bfr[ni] = *(const long*)(Bs + r * 128 + sc * 16 + half);
            }
            #pragma unroll
            for (int mi = 0; mi < 4; ++mi)
                #pragma unroll
                for (int ni = 0; ni < 4; ++ni)
                    acc[mi][ni] = __builtin_amdgcn_mfma_f32_16x16x32_fp8_fp8(
                        af[mi], bfr[ni], acc[mi][ni], 0, 0, 0);
        }
    }

    // epilogue: exp(2s); row partials + (off-diag) col partials.
    // C/D layout: col = lane&15, row = quad*4 + reg  [m89, dtype-indep]
    float cs[4] = {0.f, 0.f, 0.f, 0.f};
    float rs[4][4];
    #pragma unroll
    for (int mi = 0; mi < 4; ++mi)
        #pragma unroll
        for (int r = 0; r < 4; ++r) {
            float s = 0.f;
            #pragma unroll
            for (int ni = 0; ni < 4; ++ni) {
                const float e = __expf(2.0f * acc[mi][ni][r]);
                s += e;
                cs[ni] += e;
            }
            rs[mi][r] = s;
        }
    #pragma unroll
    for (int off = 1; off < 16; off <<= 1)
        #pragma unroll
        for (int mi = 0; mi < 4; ++mi)
            #pragma unroll
            for (int r = 0; r < 4; ++r)
                rs[mi][r] += __shfl_xor(rs[mi][r], off, 64);
    if (m16 == 0) {
        #pragma unroll
        for (int mi = 0; mi < 4; ++mi)
            #pragma unroll
            for (int r = 0; r < 4; ++r)
                atomicAdd(&denom[rowBase + wave_m * 64 + mi * 16 + quad * 4 + r],
                          rs[mi][r]);
    }
    if (bi != bj) {
        #pragma unroll
        for (int off = 16; off < 64; off <<= 1)
            #pragma unroll
            for (int ni = 0; ni < 4; ++ni)
                cs[ni] += __shfl_xor(cs[ni], off, 64);
        if (lane < 16) {
            #pragma unroll
            for (int ni = 0; ni < 4; ++ni)
                atomicAdd(&denom[colBase + wave_n * 64 + ni * 16 + m16], cs[ni]);
        }
    }

    // ---- last block to finish performs the final reduction ----
    __threadfence();
    __shared__ int lastflag;
    if (tid == 0) lastflag = (atomicAdd(counter, 1u) == NBLK - 1) ? 1 : 0;
    __syncthreads();
    if (lastflag) {
        // denom read via atomicAdd(+0) -> read at the coherent point, safe
        // across XCDs regardless of which L2 holds the line.
        float s = 0.f;
        #pragma unroll
        for (int i = 0; i < N_TOT / 256; ++i)
            s += logf(atomicAdd(&denom[i * 256 + tid], 0.0f) - E2);
        float pp = 0.f;
        #pragma unroll
        for (int i = 0; i < B_ROWS / 256; ++i) pp += pospart[i * 256 + tid];
        s -= 4.0f * pp;
        #pragma unroll
        for (int off = 32; off > 0; off >>= 1) s += __shfl_down(s, off);
        __shared__ float red[4];
        if ((tid & 63) == 0) red[tid >> 6] = s;
        __syncthreads();
        if (tid == 0)
            out[0] = (red[0] + red[1] + red[2] + red[3]) / (float)N_TOT;
    }
}

extern "C" void kernel_launch(void* const* d_in, const int* in_sizes, int n_in,
                              void* d_out, int out_size, void* d_ws, size_t ws_size,
                              hipStream_t stream) {
    const float* q = (const float*)d_in[0];
    const float* p = (const float*)d_in[1];
    // d_in[2] (neg) is normalized in the original but never used in the loss.
    float* out = (float*)d_out;

    // Workspace: Z fp8 [8192*256] (2 MiB) | denom f32 [8192] | pospart f32
    // [4096] | done-counter u32
    unsigned char* Z = (unsigned char*)d_ws;
    float* denom   = (float*)((char*)d_ws + (size_t)N_TOT * D_DIM);
    float* pospart = denom + N_TOT;
    unsigned int* counter = (unsigned int*)(pospart + B_ROWS);

    hipLaunchKernelGGL(norm_kernel, dim3(B_ROWS / 4), dim3(256), 0, stream,
                       q, p, Z, pospart, denom, counter);
    hipLaunchKernelGGL(gemm_fin, dim3(NBLK), dim3(256), 0, stream,
                       Z, denom, pospart, counter, out);
}